// Round 1
// baseline (1037.507 us; speedup 1.0000x reference)
//
#include <hip/hip_runtime.h>
#include <math.h>

// Problem constants
#define B_    1024
#define S_    256
#define COV_  512
#define H_    128
#define E_    8
#define ES_   7

// ws layout (floats)
#define W_WS_OFF   0                       // [3][1024][8]
#define COVG_OFF   24576                   // [3][1024][128]
#define USAGE_OFF  417792                  // [3][7] padded to 24
#define AT_STRIDE  260                     // 128 cols + pad, multiple of 4 (16B align for b128)

__device__ __forceinline__ float softplus_f(float x) {
    // log(1+exp(x)) stable: max(x,0) + log1p(exp(-|x|))
    return fmaxf(x, 0.0f) + log1pf(__expf(-fabsf(x)));
}

struct RouterArgs {
    const float* cov;                      // [1024][512]
    const float* Wr1[3];                   // [512][256]
    const float* br1[3];                   // [256]
    const float* Wr2[3];                   // [256][7]
    const float* br2[3];                   // [7]
    const float* Wc[3];                    // [512][128]
    const float* bc[3];                    // [128]
    float* ws;
};

// grid (128, 3), block 256: each block handles 8 consecutive b for one layer.
__global__ __launch_bounds__(256) void router_kernel(RouterArgs a) {
    const int l   = blockIdx.y;
    const int b0  = blockIdx.x * 8;
    const int tid = threadIdx.x;
    const float* __restrict__ Wr1 = a.Wr1[l];
    const float* __restrict__ Wc  = a.Wc[l];
    const float* __restrict__ covb = a.cov + b0 * COV_;

    __shared__ float hr[8][256];

    // Phase A: hr[bb][col] = relu(cov[b0+bb] @ Wr1[:,col] + br1[col])
    {
        float acc[8];
        #pragma unroll
        for (int bb = 0; bb < 8; ++bb) acc[bb] = 0.0f;
        #pragma unroll 4
        for (int k = 0; k < COV_; ++k) {
            float wv = Wr1[k * 256 + tid];           // coalesced, L2-resident
            #pragma unroll
            for (int bb = 0; bb < 8; ++bb)
                acc[bb] = fmaf(covb[bb * COV_ + k], wv, acc[bb]);  // cov: wave-uniform -> s_load
        }
        float bias = a.br1[l][tid];
        #pragma unroll
        for (int bb = 0; bb < 8; ++bb)
            hr[bb][tid] = fmaxf(acc[bb] + bias, 0.0f);
    }
    __syncthreads();

    // Phase B: logits[7] -> softmax -> w, per wave: 2 b's
    {
        const int lane = tid & 63;
        const int wave = tid >> 6;
        const int o = lane >> 3;          // 0..7 (7 invalid)
        const int g = lane & 7;
        for (int r = 0; r < 2; ++r) {
            const int bb = wave + r * 4;
            float p = 0.0f;
            if (o < ES_) {
                #pragma unroll
                for (int m = 0; m < 32; ++m) {
                    int k = g * 32 + m;
                    p = fmaf(hr[bb][k], a.Wr2[l][k * ES_ + o], p);
                }
            }
            p += __shfl_xor(p, 1);
            p += __shfl_xor(p, 2);
            p += __shfl_xor(p, 4);
            float lg = p + ((o < ES_) ? a.br2[l][o] : 0.0f);
            float v[ES_];
            #pragma unroll
            for (int oo = 0; oo < ES_; ++oo) v[oo] = __shfl(lg, oo * 8, 64);
            if (lane == 0) {
                const int b = b0 + bb;
                float mx = v[0];
                #pragma unroll
                for (int oo = 1; oo < ES_; ++oo) mx = fmaxf(mx, v[oo]);
                float ex[ES_]; float s = 0.0f;
                #pragma unroll
                for (int oo = 0; oo < ES_; ++oo) { ex[oo] = __expf(v[oo] - mx); s += ex[oo]; }
                float inv = 0.7f / s;                       // (1-UW) * softmax
                float* wout = a.ws + W_WS_OFF + (l * B_ + b) * 8;
                wout[0] = 0.3f;                             // UW/EU
                #pragma unroll
                for (int oo = 0; oo < ES_; ++oo) {
                    float rwv = ex[oo] * inv;
                    wout[1 + oo] = rwv;
                    atomicAdd(a.ws + USAGE_OFF + l * ES_ + oo, rwv);
                }
            }
        }
    }

    // Phase C: cov_gamma[b][col] = cov[b] @ Wc[:,col] + bc[col]
    {
        const int col  = tid & 127;
        const int half = tid >> 7;       // wave-uniform
        float acc[4];
        #pragma unroll
        for (int i = 0; i < 4; ++i) acc[i] = 0.0f;
        #pragma unroll 4
        for (int k = 0; k < COV_; ++k) {
            float wv = Wc[k * H_ + col];
            #pragma unroll
            for (int i = 0; i < 4; ++i)
                acc[i] = fmaf(covb[(half + 2 * i) * COV_ + k], wv, acc[i]);
        }
        float bias = a.bc[l][col];
        #pragma unroll
        for (int i = 0; i < 4; ++i) {
            int b = b0 + half + 2 * i;
            a.ws[COVG_OFF + (l * B_ + b) * H_ + col] = acc[i] + bias;
        }
    }
}

struct MainArgs {
    const float* y_t;        // [1024][256]
    const float* y0;         // [1024][256]
    const int*   t;          // [1024]
    const float* emb[3];     // [1001][128]
    const float* W1;         // [8][2][128]
    const float* W2;         // [8][128][128]
    const float* W3;         // [8][128][128]
    const float* b_[3];      // [8][128]
    const float* W4;         // [128]
    const float* b4;         // [1]
    float* ws;
    float* out;              // [1024*256] + [1] load
};

// grid 1024 (one b per block), 256 threads, ~152 KB LDS -> 1 block/CU
__global__ __launch_bounds__(256, 1) void main_kernel(MainArgs a) {
    __shared__ float At[128 * AT_STRIDE];   // h tile, transposed: At[feat][token]
    __shared__ float Wch[32 * 128];         // Weff k-chunk
    __shared__ float gl[3][128];            // gamma = emb[t[b]]
    __shared__ float cgp[3][128];           // 1 + cov_gamma
    __shared__ float bmix[3][128];          // sum_e w_e * b_e
    __shared__ float L1A[128], L1B[128], L1C[128];
    __shared__ float W4s[128];

    const int tid = threadIdx.x;
    const int b   = blockIdx.x;
    const int tb  = a.t[b];

    // ---- prologue ----
    for (int idx = tid; idx < 384; idx += 256) {
        const int l = idx >> 7, j = idx & 127;
        gl[l][j]  = a.emb[l][tb * H_ + j];
        cgp[l][j] = 1.0f + a.ws[COVG_OFF + (l * B_ + b) * H_ + j];
        const float* bl = a.b_[l];
        const float* wv = a.ws + W_WS_OFF + (l * B_ + b) * 8;
        float s = 0.0f;
        #pragma unroll
        for (int e = 0; e < E_; ++e) s = fmaf(wv[e], bl[e * H_ + j], s);
        bmix[l][j] = s;
    }
    if (tid < 128) W4s[tid] = a.W4[tid];
    __syncthreads();
    if (tid < 128) {
        const int j = tid;
        const float* wv = a.ws + W_WS_OFF + (0 * B_ + b) * 8;
        float s0 = 0.0f, s1 = 0.0f;
        #pragma unroll
        for (int e = 0; e < E_; ++e) {
            s0 = fmaf(wv[e], a.W1[e * 256 + j], s0);
            s1 = fmaf(wv[e], a.W1[e * 256 + 128 + j], s1);
        }
        float gc = gl[0][j] * cgp[0][j];
        L1A[j] = gc * s0; L1B[j] = gc * s1; L1C[j] = gc * bmix[0][j];
    }
    __syncthreads();

    // ---- layer 1 (nin=2): thread = token ----
    {
        const float x0 = a.y_t[b * S_ + tid];
        const float x1 = a.y0[b * S_ + tid];
        const float4* A4 = (const float4*)L1A;
        const float4* B4 = (const float4*)L1B;
        const float4* C4 = (const float4*)L1C;
        #pragma unroll 4
        for (int j4 = 0; j4 < 32; ++j4) {
            float4 A = A4[j4], Bv = B4[j4], C = C4[j4];
            float m0 = fmaf(x0, A.x, fmaf(x1, Bv.x, C.x));
            float m1 = fmaf(x0, A.y, fmaf(x1, Bv.y, C.y));
            float m2 = fmaf(x0, A.z, fmaf(x1, Bv.z, C.z));
            float m3 = fmaf(x0, A.w, fmaf(x1, Bv.w, C.w));
            At[(j4 * 4 + 0) * AT_STRIDE + tid] = softplus_f(m0);
            At[(j4 * 4 + 1) * AT_STRIDE + tid] = softplus_f(m1);
            At[(j4 * 4 + 2) * AT_STRIDE + tid] = softplus_f(m2);
            At[(j4 * 4 + 3) * AT_STRIDE + tid] = softplus_f(m3);
        }
    }

    // ---- layers 2 & 3: C[256 tok x 128 j] = At^T @ Weff ----
    const int tj = tid & 7;    // j-group
    const int ts = tid >> 3;   // token-group (0..31)

    for (int L = 0; L < 2; ++L) {
        const float* __restrict__ Wg = L ? a.W3 : a.W2;
        const int li = L + 1;
        const float* wv = a.ws + W_WS_OFF + (li * B_ + b) * 8;
        float we[E_];
        #pragma unroll
        for (int e = 0; e < E_; ++e) we[e] = wv[e];

        float acc[8][16];
        #pragma unroll
        for (int i = 0; i < 8; ++i)
            #pragma unroll
            for (int jq = 0; jq < 16; ++jq) acc[i][jq] = 0.0f;

        for (int kc = 0; kc < 4; ++kc) {
            __syncthreads();   // prev chunk consumed / At writes visible
            // stage Weff chunk: rows kc*32..+31
            #pragma unroll
            for (int p = 0; p < 4; ++p) {
                const int f  = p * 256 + tid;      // float4 id 0..1023
                const int il = f >> 5;             // row in chunk
                const int j4 = f & 31;
                const float* base = Wg + (kc * 32 + il) * H_ + j4 * 4;
                float4 s = {0.f, 0.f, 0.f, 0.f};
                #pragma unroll
                for (int e = 0; e < E_; ++e) {
                    float4 v = *(const float4*)(base + e * (H_ * H_));
                    s.x = fmaf(we[e], v.x, s.x);
                    s.y = fmaf(we[e], v.y, s.y);
                    s.z = fmaf(we[e], v.z, s.z);
                    s.w = fmaf(we[e], v.w, s.w);
                }
                *(float4*)(Wch + il * 128 + j4 * 4) = s;
            }
            __syncthreads();
            // GEMM partial over this k-chunk
            #pragma unroll 4
            for (int kl = 0; kl < 32; ++kl) {
                const int k = kc * 32 + kl;
                const float4* arow = (const float4*)(At + k * AT_STRIDE) + ts * 2;
                float4 a0 = arow[0], a1 = arow[1];
                float af[8] = {a0.x, a0.y, a0.z, a0.w, a1.x, a1.y, a1.z, a1.w};
                const float4* brow = (const float4*)(Wch + kl * 128) + tj;
                float4 bq0 = brow[0], bq1 = brow[8], bq2 = brow[16], bq3 = brow[24];
                float bf[16] = {bq0.x, bq0.y, bq0.z, bq0.w,
                                bq1.x, bq1.y, bq1.z, bq1.w,
                                bq2.x, bq2.y, bq2.z, bq2.w,
                                bq3.x, bq3.y, bq3.z, bq3.w};
                #pragma unroll
                for (int i = 0; i < 8; ++i)
                    #pragma unroll
                    for (int jq = 0; jq < 16; ++jq)
                        acc[i][jq] = fmaf(af[i], bf[jq], acc[i][jq]);
            }
        }
        __syncthreads();   // all GEMM reads of At done before epilogue writes

        if (L == 0) {
            // epilogue layer2: h2 = softplus(g*(acc+bmix)*(1+cg)) -> back into At
            #pragma unroll
            for (int q = 0; q < 4; ++q) {
                const int jb = 32 * q + 4 * tj;
                float4 G  = *(const float4*)&gl[1][jb];
                float4 P  = *(const float4*)&cgp[1][jb];
                float4 Bm = *(const float4*)&bmix[1][jb];
                const float Ga[4]  = {G.x, G.y, G.z, G.w};
                const float Pa[4]  = {P.x, P.y, P.z, P.w};
                const float Bma[4] = {Bm.x, Bm.y, Bm.z, Bm.w};
                #pragma unroll
                for (int jq = 0; jq < 4; ++jq) {
                    const int j = jb + jq;
                    float h[8];
                    #pragma unroll
                    for (int sl = 0; sl < 8; ++sl)
                        h[sl] = softplus_f(Ga[jq] * (acc[sl][q * 4 + jq] + Bma[jq]) * Pa[jq]);
                    float4* dst = (float4*)(At + j * AT_STRIDE + ts * 8);
                    dst[0] = make_float4(h[0], h[1], h[2], h[3]);
                    dst[1] = make_float4(h[4], h[5], h[6], h[7]);
                }
            }
        } else {
            // epilogue layer3 fused with h3 @ W4
            float po[8];
            #pragma unroll
            for (int sl = 0; sl < 8; ++sl) po[sl] = 0.0f;
            #pragma unroll
            for (int q = 0; q < 4; ++q) {
                const int jb = 32 * q + 4 * tj;
                float4 G  = *(const float4*)&gl[2][jb];
                float4 P  = *(const float4*)&cgp[2][jb];
                float4 Bm = *(const float4*)&bmix[2][jb];
                float4 W4v = *(const float4*)&W4s[jb];
                const float Ga[4]  = {G.x, G.y, G.z, G.w};
                const float Pa[4]  = {P.x, P.y, P.z, P.w};
                const float Bma[4] = {Bm.x, Bm.y, Bm.z, Bm.w};
                const float Wa[4]  = {W4v.x, W4v.y, W4v.z, W4v.w};
                #pragma unroll
                for (int jq = 0; jq < 4; ++jq) {
                    #pragma unroll
                    for (int sl = 0; sl < 8; ++sl) {
                        float h = softplus_f(Ga[jq] * (acc[sl][q * 4 + jq] + Bma[jq]) * Pa[jq]);
                        po[sl] = fmaf(h, Wa[jq], po[sl]);
                    }
                }
            }
            #pragma unroll
            for (int sl = 0; sl < 8; ++sl) {
                po[sl] += __shfl_xor(po[sl], 1);
                po[sl] += __shfl_xor(po[sl], 2);
                po[sl] += __shfl_xor(po[sl], 4);
            }
            float v = po[0];
            #pragma unroll
            for (int sl = 1; sl < 8; ++sl) if (tj == sl) v = po[sl];
            a.out[b * S_ + tid] = v + a.b4[0];
        }
    }

    // load scalar (router kernel finished before this kernel started)
    if (b == 0 && tid == 0) {
        float ld = 0.0f;
        for (int l = 0; l < 3; ++l)
            for (int o = 0; o < ES_; ++o) {
                float u = a.ws[USAGE_OFF + l * ES_ + o] * (1.0f / (float)B_);
                float d = u - (1.0f / (float)ES_);
                ld = fmaf(d, d, ld);
            }
        a.out[B_ * S_] = ld * (1.0f / (float)ES_);
    }
}

extern "C" void kernel_launch(void* const* d_in, const int* in_sizes, int n_in,
                              void* d_out, int out_size, void* d_ws, size_t ws_size,
                              hipStream_t stream) {
    (void)in_sizes; (void)n_in; (void)out_size; (void)ws_size;

    RouterArgs ra;
    ra.cov = (const float*)d_in[2];
    ra.ws  = (float*)d_ws;

    MainArgs ma;
    ma.y_t = (const float*)d_in[0];
    ma.y0  = (const float*)d_in[1];
    ma.t   = (const int*)d_in[3];
    for (int l = 0; l < 3; ++l) {
        const int base = 4 + l * 9;
        ma.emb[l] = (const float*)d_in[base + 0];
        // W handled below; b:
        ma.b_[l]  = (const float*)d_in[base + 2];
        ra.Wc[l]  = (const float*)d_in[base + 3];
        ra.bc[l]  = (const float*)d_in[base + 4];
        ra.Wr1[l] = (const float*)d_in[base + 5];
        ra.br1[l] = (const float*)d_in[base + 6];
        ra.Wr2[l] = (const float*)d_in[base + 7];
        ra.br2[l] = (const float*)d_in[base + 8];
    }
    ma.W1 = (const float*)d_in[4 + 0 * 9 + 1];
    ma.W2 = (const float*)d_in[4 + 1 * 9 + 1];
    ma.W3 = (const float*)d_in[4 + 2 * 9 + 1];
    ma.W4 = (const float*)d_in[31];
    ma.b4 = (const float*)d_in[32];
    ma.ws  = (float*)d_ws;
    ma.out = (float*)d_out;

    // zero the usage accumulators (ws is poisoned before every launch)
    hipMemsetAsync((char*)d_ws + USAGE_OFF * sizeof(float), 0, 24 * sizeof(float), stream);
    router_kernel<<<dim3(128, 3, 1), 256, 0, stream>>>(ra);
    main_kernel<<<dim3(1024, 1, 1), 256, 0, stream>>>(ma);
}

// Round 2
// 735.423 us; speedup vs baseline: 1.4108x; 1.4108x over previous
//
#include <hip/hip_runtime.h>
#include <math.h>

// Problem constants
#define B_    1024
#define S_    256
#define COV_  512
#define H_    128
#define E_    8
#define ES_   7

// ws layout (floats)
#define W_WS_OFF   0                       // [3][1024][8]
#define COVG_OFF   24576                   // [3][1024][128]
#define USAGE_OFF  417792                  // [3][7] padded to 24
#define AT_STRIDE  132                     // 128 tokens + pad (multiple of 4 for b128 alignment)

__device__ __forceinline__ float softplus_f(float x) {
    return fmaxf(x, 0.0f) + log1pf(__expf(-fabsf(x)));
}

struct RouterArgs {
    const float* cov;                      // [1024][512]
    const float* Wr1[3];                   // [512][256]
    const float* br1[3];                   // [256]
    const float* Wr2[3];                   // [256][7]
    const float* br2[3];                   // [7]
    const float* Wc[3];                    // [512][128]
    const float* bc[3];                    // [128]
    float* ws;
};

// grid (256, 3), block 384: each block = 4 consecutive b for one layer.
// Fused: hr=relu(cov@Wr1) (cols 0..255) and cov_gamma=cov@Wc (cols 256..383)
// in one column-parallel pass; cov staged in LDS (broadcast reads).
__global__ __launch_bounds__(384) void router_kernel(RouterArgs a) {
    const int l   = blockIdx.y;
    const int b0  = blockIdx.x * 4;
    const int tid = threadIdx.x;

    __shared__ float4 covs[4][COV_ / 4];   // 8 KB
    __shared__ float  hr[4][256];          // 4 KB
    __shared__ float  susage[ES_];

    // stage cov[4][512] -> LDS, coalesced float4
    for (int f = tid; f < 512; f += 384) {
        const int bb = f >> 7, k4 = f & 127;
        covs[bb][k4] = ((const float4*)(a.cov + (size_t)(b0 + bb) * COV_))[k4];
    }
    if (tid < ES_) susage[tid] = 0.0f;
    __syncthreads();

    // Phase A: column-parallel GEMV, 4 b's per thread
    {
        const float* __restrict__ Wp;
        int stride; float bias;
        if (tid < 256) { Wp = a.Wr1[l] + tid;         stride = 256; bias = a.br1[l][tid]; }
        else           { Wp = a.Wc[l]  + (tid - 256); stride = 128; bias = a.bc[l][tid - 256]; }

        float acc[4] = {0.f, 0.f, 0.f, 0.f};
        #pragma unroll 4
        for (int k4 = 0; k4 < COV_ / 4; ++k4) {
            float w0 = Wp[(4 * k4 + 0) * stride];
            float w1 = Wp[(4 * k4 + 1) * stride];
            float w2 = Wp[(4 * k4 + 2) * stride];
            float w3 = Wp[(4 * k4 + 3) * stride];
            #pragma unroll
            for (int bb = 0; bb < 4; ++bb) {
                float4 c = covs[bb][k4];               // LDS broadcast
                acc[bb] = fmaf(c.x, w0, acc[bb]);
                acc[bb] = fmaf(c.y, w1, acc[bb]);
                acc[bb] = fmaf(c.z, w2, acc[bb]);
                acc[bb] = fmaf(c.w, w3, acc[bb]);
            }
        }
        if (tid < 256) {
            #pragma unroll
            for (int bb = 0; bb < 4; ++bb)
                hr[bb][tid] = fmaxf(acc[bb] + bias, 0.0f);
        } else {
            #pragma unroll
            for (int bb = 0; bb < 4; ++bb)
                a.ws[COVG_OFF + (size_t)(l * B_ + b0 + bb) * H_ + (tid - 256)] = acc[bb] + bias;
        }
    }
    __syncthreads();

    // Phase B: router logits + softmax, one wave per b (waves 0..3)
    {
        const int wave = tid >> 6;
        const int lane = tid & 63;
        if (wave < 4) {
            const int bb = wave;
            const int o = lane >> 3;      // 0..7 (7 invalid)
            const int g = lane & 7;
            float p = 0.0f;
            if (o < ES_) {
                #pragma unroll
                for (int m = 0; m < 32; ++m) {
                    const int k = g * 32 + m;
                    p = fmaf(hr[bb][k], a.Wr2[l][k * ES_ + o], p);
                }
            }
            p += __shfl_xor(p, 1);
            p += __shfl_xor(p, 2);
            p += __shfl_xor(p, 4);
            const float lg = p + ((o < ES_) ? a.br2[l][o] : 0.0f);
            float v[ES_];
            #pragma unroll
            for (int oo = 0; oo < ES_; ++oo) v[oo] = __shfl(lg, oo * 8, 64);
            if (lane == 0) {
                const int b = b0 + bb;
                float mx = v[0];
                #pragma unroll
                for (int oo = 1; oo < ES_; ++oo) mx = fmaxf(mx, v[oo]);
                float ex[ES_]; float s = 0.0f;
                #pragma unroll
                for (int oo = 0; oo < ES_; ++oo) { ex[oo] = __expf(v[oo] - mx); s += ex[oo]; }
                const float inv = 0.7f / s;            // (1-UW) * softmax
                float* wout = a.ws + W_WS_OFF + (size_t)(l * B_ + b) * 8;
                wout[0] = 0.3f;                        // UW/EU
                #pragma unroll
                for (int oo = 0; oo < ES_; ++oo) {
                    const float rwv = ex[oo] * inv;
                    wout[1 + oo] = rwv;
                    atomicAdd(&susage[oo], rwv);       // LDS pre-reduction
                }
            }
        }
    }
    __syncthreads();
    if (tid < ES_) atomicAdd(a.ws + USAGE_OFF + l * ES_ + tid, susage[tid]);
}

struct MainArgs {
    const float* y_t;        // [1024][256]
    const float* y0;         // [1024][256]
    const int*   t;          // [1024]
    const float* emb[3];     // [1001][128]
    const float* W1;         // [8][2][128]
    const float* W2;         // [8][128][128]
    const float* W3;         // [8][128][128]
    const float* b_[3];      // [8][128]
    const float* W4;         // [128]
    const float* b4;         // [1]
    float* ws;
    float* out;              // [1024*256] + [1] load
};

// grid 2048 (2 token-halves per b), 256 threads.
// LDS = 67584 (At) + 8192 (Wch, aliases L1A/B/C) + 4608 + 512 = 80896 B
// <= 80 KiB  ->  2 blocks/CU, 8 waves/CU.
__global__ __launch_bounds__(256, 2) void main_kernel(MainArgs a) {
    __shared__ float At[128 * AT_STRIDE];   // h tile: At[feat][token_local], 128 tokens
    __shared__ float Wch[16 * 128];         // Weff k-chunk; aliased: L1A=Wch, L1B=+128, L1C=+256
    __shared__ float gl[3][128];            // gamma = emb[t[b]]
    __shared__ float cgp[3][128];           // 1 + cov_gamma
    __shared__ float bmix[3][128];          // sum_e w_e * b_e
    __shared__ float W4s[128];

    const int tid = threadIdx.x;
    const int b   = blockIdx.x >> 1;
    const int s0  = (blockIdx.x & 1) * 128;   // token-half offset
    const int tb  = a.t[b];

    // ---- prologue ----
    for (int idx = tid; idx < 384; idx += 256) {
        const int l = idx >> 7, j = idx & 127;
        gl[l][j]  = a.emb[l][tb * H_ + j];
        cgp[l][j] = 1.0f + a.ws[COVG_OFF + (size_t)(l * B_ + b) * H_ + j];
        const float* bl = a.b_[l];
        const float* wv = a.ws + W_WS_OFF + (size_t)(l * B_ + b) * 8;
        float s = 0.0f;
        #pragma unroll
        for (int e = 0; e < E_; ++e) s = fmaf(wv[e], bl[e * H_ + j], s);
        bmix[l][j] = s;
    }
    if (tid < 128) W4s[tid] = a.W4[tid];
    __syncthreads();
    if (tid < 128) {
        const int j = tid;
        const float* wv = a.ws + W_WS_OFF + (size_t)(0 * B_ + b) * 8;
        float sA = 0.0f, sB = 0.0f;
        #pragma unroll
        for (int e = 0; e < E_; ++e) {
            sA = fmaf(wv[e], a.W1[e * 256 + j], sA);
            sB = fmaf(wv[e], a.W1[e * 256 + 128 + j], sB);
        }
        const float gc = gl[0][j] * cgp[0][j];
        Wch[j]       = gc * sA;      // L1A
        Wch[128 + j] = gc * sB;      // L1B
        Wch[256 + j] = gc * bmix[0][j];  // L1C
    }
    __syncthreads();

    // ---- layer 1 (nin=2): 128 tokens, 2 threads per token (j-halves) ----
    {
        const int tl = tid & 127;
        const int j4h = (tid >> 7) * 16;   // float4 offset: 0 or 16
        const float x0 = a.y_t[b * S_ + s0 + tl];
        const float x1 = a.y0[b * S_ + s0 + tl];
        const float4* A4 = (const float4*)(Wch);
        const float4* B4 = (const float4*)(Wch + 128);
        const float4* C4 = (const float4*)(Wch + 256);
        #pragma unroll 4
        for (int j4 = j4h; j4 < j4h + 16; ++j4) {
            float4 A = A4[j4], Bv = B4[j4], C = C4[j4];
            float m0 = fmaf(x0, A.x, fmaf(x1, Bv.x, C.x));
            float m1 = fmaf(x0, A.y, fmaf(x1, Bv.y, C.y));
            float m2 = fmaf(x0, A.z, fmaf(x1, Bv.z, C.z));
            float m3 = fmaf(x0, A.w, fmaf(x1, Bv.w, C.w));
            At[(j4 * 4 + 0) * AT_STRIDE + tl] = softplus_f(m0);
            At[(j4 * 4 + 1) * AT_STRIDE + tl] = softplus_f(m1);
            At[(j4 * 4 + 2) * AT_STRIDE + tl] = softplus_f(m2);
            At[(j4 * 4 + 3) * AT_STRIDE + tl] = softplus_f(m3);
        }
    }

    // ---- layers 2 & 3: C[128 tok x 128 j] = At^T @ Weff ----
    // thread (ts,tj): tokens ts*8..ts*8+7, cols j = 4*tj+c + 64*q (q=0,1; c=0..3)
    const int tj = tid & 15;
    const int ts = tid >> 4;

    for (int L = 0; L < 2; ++L) {
        const float* __restrict__ Wg = L ? a.W3 : a.W2;
        const int li = L + 1;
        const float* wv = a.ws + W_WS_OFF + (size_t)(li * B_ + b) * 8;
        float we[E_];
        #pragma unroll
        for (int e = 0; e < E_; ++e) we[e] = wv[e];

        float acc[8][8];
        #pragma unroll
        for (int i = 0; i < 8; ++i)
            #pragma unroll
            for (int jq = 0; jq < 8; ++jq) acc[i][jq] = 0.0f;

        for (int kc = 0; kc < 8; ++kc) {
            __syncthreads();   // prev chunk consumed / At (layer-1 or epilogue) visible
            // stage Weff chunk: rows kc*16 .. kc*16+15
            #pragma unroll
            for (int p = 0; p < 2; ++p) {
                const int f  = p * 256 + tid;      // float4 id 0..511
                const int il = f >> 5;             // row in chunk
                const int j4 = f & 31;
                const float* base = Wg + (size_t)(kc * 16 + il) * H_ + j4 * 4;
                float4 s = {0.f, 0.f, 0.f, 0.f};
                #pragma unroll
                for (int e = 0; e < E_; ++e) {
                    float4 v = *(const float4*)(base + (size_t)e * (H_ * H_));
                    s.x = fmaf(we[e], v.x, s.x);
                    s.y = fmaf(we[e], v.y, s.y);
                    s.z = fmaf(we[e], v.z, s.z);
                    s.w = fmaf(we[e], v.w, s.w);
                }
                *(float4*)(Wch + il * 128 + j4 * 4) = s;
            }
            __syncthreads();
            // GEMM partial over this k-chunk
            const float* Abase = At + (kc * 16) * AT_STRIDE + ts * 8;
            const float4* Bb = (const float4*)Wch + tj;
            #pragma unroll 4
            for (int kl = 0; kl < 16; ++kl) {
                const float4* ar = (const float4*)(Abase + kl * AT_STRIDE);
                float4 a0 = ar[0], a1 = ar[1];
                float af[8] = {a0.x, a0.y, a0.z, a0.w, a1.x, a1.y, a1.z, a1.w};
                float4 bq0 = Bb[kl * 32], bq1 = Bb[kl * 32 + 16];
                float bf[8] = {bq0.x, bq0.y, bq0.z, bq0.w,
                               bq1.x, bq1.y, bq1.z, bq1.w};
                #pragma unroll
                for (int i = 0; i < 8; ++i)
                    #pragma unroll
                    for (int jq = 0; jq < 8; ++jq)
                        acc[i][jq] = fmaf(af[i], bf[jq], acc[i][jq]);
            }
        }
        __syncthreads();   // all GEMM reads done before epilogue writes At

        if (L == 0) {
            // epilogue layer2: h2 = softplus(g*(acc+bmix)*(1+cg)) -> back into At
            #pragma unroll
            for (int q = 0; q < 2; ++q) {
                const int jb = q * 64 + 4 * tj;
                float4 G  = *(const float4*)&gl[1][jb];
                float4 P  = *(const float4*)&cgp[1][jb];
                float4 Bm = *(const float4*)&bmix[1][jb];
                const float Ga[4]  = {G.x, G.y, G.z, G.w};
                const float Pa[4]  = {P.x, P.y, P.z, P.w};
                const float Bma[4] = {Bm.x, Bm.y, Bm.z, Bm.w};
                #pragma unroll
                for (int c = 0; c < 4; ++c) {
                    const int j = jb + c;
                    float h[8];
                    #pragma unroll
                    for (int i = 0; i < 8; ++i)
                        h[i] = softplus_f(Ga[c] * (acc[i][q * 4 + c] + Bma[c]) * Pa[c]);
                    float4* dst = (float4*)(At + j * AT_STRIDE + ts * 8);
                    dst[0] = make_float4(h[0], h[1], h[2], h[3]);
                    dst[1] = make_float4(h[4], h[5], h[6], h[7]);
                }
            }
        } else {
            // epilogue layer3 fused with h3 @ W4
            float po[8];
            #pragma unroll
            for (int i = 0; i < 8; ++i) po[i] = 0.0f;
            #pragma unroll
            for (int q = 0; q < 2; ++q) {
                const int jb = q * 64 + 4 * tj;
                float4 G  = *(const float4*)&gl[2][jb];
                float4 P  = *(const float4*)&cgp[2][jb];
                float4 Bm = *(const float4*)&bmix[2][jb];
                float4 Wv = *(const float4*)&W4s[jb];
                const float Ga[4]  = {G.x, G.y, G.z, G.w};
                const float Pa[4]  = {P.x, P.y, P.z, P.w};
                const float Bma[4] = {Bm.x, Bm.y, Bm.z, Bm.w};
                const float Wa[4]  = {Wv.x, Wv.y, Wv.z, Wv.w};
                #pragma unroll
                for (int c = 0; c < 4; ++c) {
                    #pragma unroll
                    for (int i = 0; i < 8; ++i) {
                        float h = softplus_f(Ga[c] * (acc[i][q * 4 + c] + Bma[c]) * Pa[c]);
                        po[i] = fmaf(h, Wa[c], po[i]);
                    }
                }
            }
            // reduce over tj (16 lanes: xor 1,2,4,8 within lane&15 group)
            #pragma unroll
            for (int i = 0; i < 8; ++i) {
                po[i] += __shfl_xor(po[i], 1);
                po[i] += __shfl_xor(po[i], 2);
                po[i] += __shfl_xor(po[i], 4);
                po[i] += __shfl_xor(po[i], 8);
            }
            float v = po[0];
            #pragma unroll
            for (int i = 1; i < 8; ++i) if (tj == i) v = po[i];
            if (tj < 8)
                a.out[b * S_ + s0 + ts * 8 + tj] = v + a.b4[0];
        }
    }

    // load scalar (router kernel finished before this kernel started)
    if (blockIdx.x == 0 && tid == 0) {
        float ld = 0.0f;
        for (int l = 0; l < 3; ++l)
            for (int o = 0; o < ES_; ++o) {
                float u = a.ws[USAGE_OFF + l * ES_ + o] * (1.0f / (float)B_);
                float d = u - (1.0f / (float)ES_);
                ld = fmaf(d, d, ld);
            }
        a.out[B_ * S_] = ld * (1.0f / (float)ES_);
    }
}

extern "C" void kernel_launch(void* const* d_in, const int* in_sizes, int n_in,
                              void* d_out, int out_size, void* d_ws, size_t ws_size,
                              hipStream_t stream) {
    (void)in_sizes; (void)n_in; (void)out_size; (void)ws_size;

    RouterArgs ra;
    ra.cov = (const float*)d_in[2];
    ra.ws  = (float*)d_ws;

    MainArgs ma;
    ma.y_t = (const float*)d_in[0];
    ma.y0  = (const float*)d_in[1];
    ma.t   = (const int*)d_in[3];
    for (int l = 0; l < 3; ++l) {
        const int base = 4 + l * 9;
        ma.emb[l] = (const float*)d_in[base + 0];
        ma.b_[l]  = (const float*)d_in[base + 2];
        ra.Wc[l]  = (const float*)d_in[base + 3];
        ra.bc[l]  = (const float*)d_in[base + 4];
        ra.Wr1[l] = (const float*)d_in[base + 5];
        ra.br1[l] = (const float*)d_in[base + 6];
        ra.Wr2[l] = (const float*)d_in[base + 7];
        ra.br2[l] = (const float*)d_in[base + 8];
    }
    ma.W1 = (const float*)d_in[4 + 0 * 9 + 1];
    ma.W2 = (const float*)d_in[4 + 1 * 9 + 1];
    ma.W3 = (const float*)d_in[4 + 2 * 9 + 1];
    ma.W4 = (const float*)d_in[31];
    ma.b4 = (const float*)d_in[32];
    ma.ws  = (float*)d_ws;
    ma.out = (float*)d_out;

    // zero the usage accumulators (ws is poisoned before every launch)
    hipMemsetAsync((char*)d_ws + USAGE_OFF * sizeof(float), 0, 24 * sizeof(float), stream);
    router_kernel<<<dim3(256, 3, 1), 384, 0, stream>>>(ra);
    main_kernel<<<dim3(2048, 1, 1), 256, 0, stream>>>(ma);
}

// Round 3
// 507.336 us; speedup vs baseline: 2.0450x; 1.4496x over previous
//
#include <hip/hip_runtime.h>
#include <math.h>

// Problem constants
#define B_    1024
#define S_    256
#define COV_  512
#define H_    128
#define E_    8
#define ES_   7

// ws layout (floats)
#define W_WS_OFF   0                       // [3][1024][8]
#define COVG_OFF   24576                   // [3][1024][128]
#define USAGE_OFF  417792                  // [3][7] padded

#define AT_STRIDE  136                     // 128 k + 8 pad (bf16), row = 272 B (16B aligned, even banks)
#define WT_STRIDE  40                      // 32 k + 8 pad (bf16), row = 80 B  (16B aligned, even banks)

typedef __attribute__((ext_vector_type(8))) short bf16x8;  // 8 bf16 = 4 VGPRs (MFMA A/B frag)
typedef __attribute__((ext_vector_type(4))) float f32x4;   // MFMA C/D frag

__device__ __forceinline__ float softplus_f(float x) {
    return fmaxf(x, 0.0f) + log1pf(__expf(-fabsf(x)));
}
__device__ __forceinline__ unsigned bf16_rne(float x) {
    unsigned u = __float_as_uint(x);
    return (u + 0x7FFFu + ((u >> 16) & 1u)) >> 16;
}
__device__ __forceinline__ void split_bf16(float x, unsigned &hi, unsigned &lo) {
    hi = bf16_rne(x);
    float hf = __uint_as_float(hi << 16);
    lo = bf16_rne(x - hf);
}

struct RouterArgs {
    const float* cov;                      // [1024][512]
    const float* Wr1[3];                   // [512][256]
    const float* br1[3];                   // [256]
    const float* Wr2[3];                   // [256][7]
    const float* br2[3];                   // [7]
    const float* Wc[3];                    // [512][128]
    const float* bc[3];                    // [128]
    float* ws;
};

// grid (256, 3), block 192 (3 waves): 4 b's, 2 columns per thread.
// Cols 0..255 = Wr1 (hr), 256..383 = Wc (cov_gamma). Per k4: 8 global loads +
// 4 LDS b128 + 32 FMA -> VALU-bound ratio.
__global__ __launch_bounds__(192) void router_kernel(RouterArgs a) {
    const int l   = blockIdx.y;
    const int b0  = blockIdx.x * 4;
    const int tid = threadIdx.x;

    __shared__ float4 covs[4][COV_ / 4];   // 8 KB
    __shared__ float  hr[4][256];          // 4 KB
    __shared__ float  susage[ES_];

    for (int f = tid; f < 512; f += 192) {
        const int bb = f >> 7, k4 = f & 127;
        covs[bb][k4] = ((const float4*)(a.cov + (size_t)(b0 + bb) * COV_))[k4];
    }
    if (tid < ES_) susage[tid] = 0.0f;
    __syncthreads();

    // Phase A: two columns per thread, 4 b's
    {
        const int c0 = tid, c1 = tid + 192;
        const float* P0 = a.Wr1[l] + c0;
        const int st0 = 256;
        const float bi0 = a.br1[l][c0];
        const float* P1;
        int st1; float bi1; bool c1_hr = (c1 < 256);
        if (c1_hr) { P1 = a.Wr1[l] + c1;       st1 = 256; bi1 = a.br1[l][c1]; }
        else       { P1 = a.Wc[l] + (c1 - 256); st1 = 128; bi1 = a.bc[l][c1 - 256]; }

        float a0[4] = {0.f,0.f,0.f,0.f}, a1[4] = {0.f,0.f,0.f,0.f};
        #pragma unroll 2
        for (int k4 = 0; k4 < COV_ / 4; ++k4) {
            float w00 = P0[(4*k4+0)*st0], w01 = P0[(4*k4+1)*st0];
            float w02 = P0[(4*k4+2)*st0], w03 = P0[(4*k4+3)*st0];
            float w10 = P1[(4*k4+0)*st1], w11 = P1[(4*k4+1)*st1];
            float w12 = P1[(4*k4+2)*st1], w13 = P1[(4*k4+3)*st1];
            #pragma unroll
            for (int bb = 0; bb < 4; ++bb) {
                float4 c = covs[bb][k4];           // broadcast (uniform addr)
                a0[bb] = fmaf(c.x, w00, a0[bb]);
                a0[bb] = fmaf(c.y, w01, a0[bb]);
                a0[bb] = fmaf(c.z, w02, a0[bb]);
                a0[bb] = fmaf(c.w, w03, a0[bb]);
                a1[bb] = fmaf(c.x, w10, a1[bb]);
                a1[bb] = fmaf(c.y, w11, a1[bb]);
                a1[bb] = fmaf(c.z, w12, a1[bb]);
                a1[bb] = fmaf(c.w, w13, a1[bb]);
            }
        }
        #pragma unroll
        for (int bb = 0; bb < 4; ++bb) hr[bb][c0] = fmaxf(a0[bb] + bi0, 0.0f);
        if (c1_hr) {
            #pragma unroll
            for (int bb = 0; bb < 4; ++bb) hr[bb][c1] = fmaxf(a1[bb] + bi1, 0.0f);
        } else {
            #pragma unroll
            for (int bb = 0; bb < 4; ++bb)
                a.ws[COVG_OFF + (size_t)(l * B_ + b0 + bb) * H_ + (c1 - 256)] = a1[bb] + bi1;
        }
    }
    __syncthreads();

    // Phase B: router logits + softmax (wave 0; 16 lanes per b)
    if (tid < 64) {
        const int bb = tid >> 4, o = tid & 15;
        float p = -1e30f;
        if (o < ES_) {
            float s = 0.0f;
            #pragma unroll 4
            for (int k = 0; k < 256; ++k)
                s = fmaf(hr[bb][k], a.Wr2[l][k * ES_ + o], s);
            p = s + a.br2[l][o];
        }
        float mx = p;
        mx = fmaxf(mx, __shfl_xor(mx, 1));
        mx = fmaxf(mx, __shfl_xor(mx, 2));
        mx = fmaxf(mx, __shfl_xor(mx, 4));
        mx = fmaxf(mx, __shfl_xor(mx, 8));
        float ex = (o < ES_) ? __expf(p - mx) : 0.0f;
        float s = ex;
        s += __shfl_xor(s, 1);
        s += __shfl_xor(s, 2);
        s += __shfl_xor(s, 4);
        s += __shfl_xor(s, 8);
        float* wout = a.ws + W_WS_OFF + (size_t)(l * B_ + b0 + bb) * 8;
        if (o == 7) wout[0] = 0.3f;            // UW/EU (idle lane)
        if (o < ES_) {
            float rwv = ex * (0.7f / s);       // (1-UW)*softmax
            wout[1 + o] = rwv;
            atomicAdd(&susage[o], rwv);
        }
    }
    __syncthreads();
    if (tid < ES_) atomicAdd(a.ws + USAGE_OFF + l * ES_ + tid, susage[tid]);
}

struct MainArgs {
    const float* y_t;        // [1024][256]
    const float* y0;         // [1024][256]
    const int*   t;          // [1024]
    const float* emb[3];     // [1001][128]
    const float* W1;         // [8][2][128]
    const float* W2;         // [8][128][128]
    const float* W3;         // [8][128][128]
    const float* b_[3];      // [8][128]
    const float* W4;         // [128]
    const float* b4;         // [1]
    float* ws;
    float* out;              // [1024*256] + [1] load
};

// grid 1024 (one b per block), 512 threads (8 waves), ~148.5 KB LDS -> 1 block/CU.
// bf16x3 emulated-fp32 GEMM on the matrix cores:
//   A (h, tokens x k) and Weff (k x n) each split hi/lo bf16;
//   D += Ahi*Bhi + Ahi*Blo + Alo*Bhi  via v_mfma_f32_16x16x32_bf16.
// Wave tile: 64 tok x 64 n (4x4 16x16 tiles); waves 4x2 over 256x128.
__global__ __launch_bounds__(512, 2) void main_kernel(MainArgs a) {
    __shared__ unsigned short Ahi[256 * AT_STRIDE];   // 69632 B
    __shared__ unsigned short Alo[256 * AT_STRIDE];   // 69632 B
    __shared__ unsigned short WtBuf[2][128 * WT_STRIDE]; // 10240 B (hi, lo); aliased: L1 coeffs / pos
    __shared__ float GPs[2][128];    // gamma*(1+covg) for layers 2,3
    __shared__ float GPBs[2][128];   // GPs * bmix
    __shared__ float W4s[128];

    const int tid  = threadIdx.x;
    const int b    = blockIdx.x;
    const int lane = tid & 63;
    const int w    = tid >> 6;
    const int wm   = w >> 1;        // 0..3: token block (64)
    const int wn   = w & 1;         // 0..1: n block (64)
    const int nl   = lane & 15;
    const int quad = lane >> 4;
    const int tb   = a.t[b];

    float* L1f = (float*)WtBuf;     // [0:128)=A, [128:256)=B, [256:384)=C coeffs

    // ---- prologue: per-layer modulation vectors ----
    if (tid < 384) {
        const int l = tid >> 7, j = tid & 127;
        const float* wv = a.ws + W_WS_OFF + (size_t)(l * B_ + b) * 8;
        const float gamma = a.emb[l][tb * H_ + j];
        const float covg  = a.ws[COVG_OFF + (size_t)(l * B_ + b) * H_ + j];
        const float gp = gamma * (1.0f + covg);
        const float* bl = a.b_[l];
        float bm = 0.0f;
        #pragma unroll
        for (int e = 0; e < E_; ++e) bm = fmaf(wv[e], bl[e * H_ + j], bm);
        if (l == 0) {
            float s0 = 0.0f, s1 = 0.0f;
            #pragma unroll
            for (int e = 0; e < E_; ++e) {
                s0 = fmaf(wv[e], a.W1[e * 256 + j], s0);
                s1 = fmaf(wv[e], a.W1[e * 256 + 128 + j], s1);
            }
            L1f[j]       = gp * s0;
            L1f[128 + j] = gp * s1;
            L1f[256 + j] = gp * bm;
        } else {
            GPs[l - 1][j]  = gp;
            GPBs[l - 1][j] = gp * bm;
        }
    }
    if (tid < 128) W4s[tid] = a.W4[tid];
    __syncthreads();

    // ---- layer 1 (nin=2): 2 threads per token, write At hi/lo ----
    {
        const int tok = tid >> 1;
        const int jh  = (tid & 1) * 64;
        const float x0 = a.y_t[b * S_ + tok];
        const float x1 = a.y0[b * S_ + tok];
        #pragma unroll
        for (int g = 0; g < 8; ++g) {
            const int jb = jh + g * 8;
            unsigned hp[4], lp[4];
            #pragma unroll
            for (int p = 0; p < 4; ++p) {
                const int j0 = jb + 2 * p;
                float m0 = fmaf(x0, L1f[j0],     fmaf(x1, L1f[128 + j0],     L1f[256 + j0]));
                float m1 = fmaf(x0, L1f[j0 + 1], fmaf(x1, L1f[128 + j0 + 1], L1f[256 + j0 + 1]));
                unsigned h0, l0, h1, l1;
                split_bf16(softplus_f(m0), h0, l0);
                split_bf16(softplus_f(m1), h1, l1);
                hp[p] = h0 | (h1 << 16);
                lp[p] = l0 | (l1 << 16);
            }
            *(uint4*)&Ahi[tok * AT_STRIDE + jb] = make_uint4(hp[0], hp[1], hp[2], hp[3]);
            *(uint4*)&Alo[tok * AT_STRIDE + jb] = make_uint4(lp[0], lp[1], lp[2], lp[3]);
        }
    }
    // (first chunk barrier below synchronizes At)

    const int bj  = tid & 127;     // Weff-build: column j
    const int bkg = tid >> 7;      // Weff-build: k-group (8 k's)

    for (int L = 0; L < 2; ++L) {
        const float* __restrict__ Wg = L ? a.W3 : a.W2;
        const float* wv = a.ws + W_WS_OFF + (size_t)((L + 1) * B_ + b) * 8;
        float we[E_];
        #pragma unroll
        for (int e = 0; e < E_; ++e) we[e] = wv[e];

        f32x4 acc[4][4];
        #pragma unroll
        for (int mt = 0; mt < 4; ++mt)
            #pragma unroll
            for (int nt = 0; nt < 4; ++nt)
                acc[mt][nt] = (f32x4){0.f, 0.f, 0.f, 0.f};

        // Weff chunk builder: 8 k's x 1 column per thread -> packed hi/lo dwords
        unsigned bh[4], blo_[4];
        auto build = [&](int kc) {
            float bacc[8] = {0,0,0,0,0,0,0,0};
            const float* base = Wg + (size_t)(kc * 32 + bkg * 8) * H_ + bj;
            #pragma unroll
            for (int e = 0; e < E_; ++e) {
                const float* p = base + (size_t)e * (H_ * H_);
                const float wE = we[e];
                #pragma unroll
                for (int i = 0; i < 8; ++i)
                    bacc[i] = fmaf(wE, p[i * H_], bacc[i]);
            }
            #pragma unroll
            for (int i = 0; i < 4; ++i) {
                unsigned h0, l0, h1, l1;
                split_bf16(bacc[2 * i],     h0, l0);
                split_bf16(bacc[2 * i + 1], h1, l1);
                bh[i]   = h0 | (h1 << 16);
                blo_[i] = l0 | (l1 << 16);
            }
        };

        build(0);

        for (int kc = 0; kc < 4; ++kc) {
            __syncthreads();   // prev GEMM done reading Wt; At writes visible (kc==0)
            *(uint4*)&WtBuf[0][bj * WT_STRIDE + bkg * 8] = make_uint4(bh[0], bh[1], bh[2], bh[3]);
            *(uint4*)&WtBuf[1][bj * WT_STRIDE + bkg * 8] = make_uint4(blo_[0], blo_[1], blo_[2], blo_[3]);
            __syncthreads();

            // GEMM k-step (K=32)
            const int ka = kc * 32 + quad * 8;
            bf16x8 Af[4], Al[4], Bf[4], Bl[4];
            #pragma unroll
            for (int mt = 0; mt < 4; ++mt) {
                const int row = (wm * 64 + mt * 16 + nl) * AT_STRIDE + ka;
                Af[mt] = *(const bf16x8*)&Ahi[row];
                Al[mt] = *(const bf16x8*)&Alo[row];
            }
            #pragma unroll
            for (int nt = 0; nt < 4; ++nt) {
                const int row = (wn * 64 + nt * 16 + nl) * WT_STRIDE + quad * 8;
                Bf[nt] = *(const bf16x8*)&WtBuf[0][row];
                Bl[nt] = *(const bf16x8*)&WtBuf[1][row];
            }
            #pragma unroll
            for (int mt = 0; mt < 4; ++mt)
                #pragma unroll
                for (int nt = 0; nt < 4; ++nt) {
                    acc[mt][nt] = __builtin_amdgcn_mfma_f32_16x16x32_bf16(Af[mt], Bf[nt], acc[mt][nt], 0, 0, 0);
                    acc[mt][nt] = __builtin_amdgcn_mfma_f32_16x16x32_bf16(Af[mt], Bl[nt], acc[mt][nt], 0, 0, 0);
                    acc[mt][nt] = __builtin_amdgcn_mfma_f32_16x16x32_bf16(Al[mt], Bf[nt], acc[mt][nt], 0, 0, 0);
                }

            if (kc < 3) build(kc + 1);
        }
        __syncthreads();   // all GEMM reads of At / Wt done

        if (L == 0) {
            // epilogue layer2 -> At (hi/lo) ; C layout: n=lane&15(+16*nt), tok=quad*4+reg(+16*mt)
            #pragma unroll
            for (int nt = 0; nt < 4; ++nt) {
                const int n = wn * 64 + nt * 16 + nl;
                const float gp = GPs[0][n], gpb = GPBs[0][n];
                #pragma unroll
                for (int mt = 0; mt < 4; ++mt) {
                    #pragma unroll
                    for (int r = 0; r < 4; ++r) {
                        const int tok = wm * 64 + mt * 16 + quad * 4 + r;
                        const float h = softplus_f(fmaf(gp, acc[mt][nt][r], gpb));
                        unsigned hh, ll;
                        split_bf16(h, hh, ll);
                        Ahi[tok * AT_STRIDE + n] = (unsigned short)hh;
                        Alo[tok * AT_STRIDE + n] = (unsigned short)ll;
                    }
                }
            }
        } else {
            // epilogue layer3 fused with h3 @ W4
            float po[4][4];
            #pragma unroll
            for (int mt = 0; mt < 4; ++mt)
                #pragma unroll
                for (int r = 0; r < 4; ++r) po[mt][r] = 0.0f;
            #pragma unroll
            for (int nt = 0; nt < 4; ++nt) {
                const int n = wn * 64 + nt * 16 + nl;
                const float gp = GPs[1][n], gpb = GPBs[1][n], w4 = W4s[n];
                #pragma unroll
                for (int mt = 0; mt < 4; ++mt)
                    #pragma unroll
                    for (int r = 0; r < 4; ++r) {
                        const float h = softplus_f(fmaf(gp, acc[mt][nt][r], gpb));
                        po[mt][r] = fmaf(h, w4, po[mt][r]);
                    }
            }
            #pragma unroll
            for (int mt = 0; mt < 4; ++mt)
                #pragma unroll
                for (int r = 0; r < 4; ++r) {
                    po[mt][r] += __shfl_xor(po[mt][r], 1);
                    po[mt][r] += __shfl_xor(po[mt][r], 2);
                    po[mt][r] += __shfl_xor(po[mt][r], 4);
                    po[mt][r] += __shfl_xor(po[mt][r], 8);
                }
            float* pos = (float*)WtBuf;   // Wt free after post-loop barrier
            if (nl == 0) {
                #pragma unroll
                for (int mt = 0; mt < 4; ++mt)
                    #pragma unroll
                    for (int r = 0; r < 4; ++r)
                        pos[(wm * 64 + mt * 16 + quad * 4 + r) * 2 + wn] = po[mt][r];
            }
            __syncthreads();
            if (tid < 256)
                a.out[b * S_ + tid] = pos[2 * tid] + pos[2 * tid + 1] + a.b4[0];
        }
    }

    // load-balance scalar (router completed before this kernel)
    if (b == 0 && tid == 0) {
        float ld = 0.0f;
        for (int l = 0; l < 3; ++l)
            for (int o = 0; o < ES_; ++o) {
                float u = a.ws[USAGE_OFF + l * ES_ + o] * (1.0f / (float)B_);
                float d = u - (1.0f / (float)ES_);
                ld = fmaf(d, d, ld);
            }
        a.out[B_ * S_] = ld * (1.0f / (float)ES_);
    }
}

extern "C" void kernel_launch(void* const* d_in, const int* in_sizes, int n_in,
                              void* d_out, int out_size, void* d_ws, size_t ws_size,
                              hipStream_t stream) {
    (void)in_sizes; (void)n_in; (void)out_size; (void)ws_size;

    RouterArgs ra;
    ra.cov = (const float*)d_in[2];
    ra.ws  = (float*)d_ws;

    MainArgs ma;
    ma.y_t = (const float*)d_in[0];
    ma.y0  = (const float*)d_in[1];
    ma.t   = (const int*)d_in[3];
    for (int l = 0; l < 3; ++l) {
        const int base = 4 + l * 9;
        ma.emb[l] = (const float*)d_in[base + 0];
        ma.b_[l]  = (const float*)d_in[base + 2];
        ra.Wc[l]  = (const float*)d_in[base + 3];
        ra.bc[l]  = (const float*)d_in[base + 4];
        ra.Wr1[l] = (const float*)d_in[base + 5];
        ra.br1[l] = (const float*)d_in[base + 6];
        ra.Wr2[l] = (const float*)d_in[base + 7];
        ra.br2[l] = (const float*)d_in[base + 8];
    }
    ma.W1 = (const float*)d_in[4 + 0 * 9 + 1];
    ma.W2 = (const float*)d_in[4 + 1 * 9 + 1];
    ma.W3 = (const float*)d_in[4 + 2 * 9 + 1];
    ma.W4 = (const float*)d_in[31];
    ma.b4 = (const float*)d_in[32];
    ma.ws  = (float*)d_ws;
    ma.out = (float*)d_out;

    hipMemsetAsync((char*)d_ws + USAGE_OFF * sizeof(float), 0, 24 * sizeof(float), stream);
    router_kernel<<<dim3(256, 3, 1), 192, 0, stream>>>(ra);
    main_kernel<<<dim3(1024, 1, 1), 512, 0, stream>>>(ma);
}

// Round 5
// 322.486 us; speedup vs baseline: 3.2172x; 1.5732x over previous
//
#include <hip/hip_runtime.h>
#include <hip/hip_bf16.h>
#include <math.h>

// Problem constants
#define B_    1024
#define S_    256
#define COV_  512
#define H_    128
#define E_    8
#define ES_   7

// ws layout (floats)
#define W_WS_OFF   0                       // [3][1024][8]
#define COVG_OFF   24576                   // [3][1024][128]
#define USAGE_OFF  417792                  // [3][7] padded

#define AT_STRIDE  136                     // 128 k + 8 pad (bf16), row = 272 B (16B aligned)
#define WT_STRIDE  40                      // 32 k + 8 pad (bf16), row = 80 B  (16B aligned)

typedef __attribute__((ext_vector_type(8))) short bf16x8;  // 8 bf16 = 4 VGPRs (MFMA A/B frag)
typedef __attribute__((ext_vector_type(4))) float f32x4;   // MFMA C/D frag

// Fast softplus: 2 HW transcendentals (v_exp_f32 / v_log_f32) + few VALU.
// sp(x) = max(x,0) + log(1 + exp(-|x|));  |err| ~ 1e-7 abs (HW exp/log ~1 ulp).
// NOTE: __exp2f/__log2f collide with glibc math.h macros on this toolchain;
// __expf/__logf are the HIP device fast intrinsics and compile clean.
__device__ __forceinline__ float softplus_f(float x) {
    return fmaxf(x, 0.0f) + __logf(1.0f + __expf(-fabsf(x)));
}

// v_cvt_pk_bf16_f32: pack two fp32 -> two bf16 (RNE), a in low 16, b in high 16.
__device__ __forceinline__ unsigned pk2_bf16(float a, float b) {
    __hip_bfloat162 h = __float22bfloat162_rn(make_float2(a, b));
    return *reinterpret_cast<unsigned*>(&h);
}
// hi/lo split of a pair: hi = rne_bf16(x), lo = rne_bf16(x - hi). ~6 instr/pair.
__device__ __forceinline__ void split_pair(float a, float b, unsigned &hi, unsigned &lo) {
    hi = pk2_bf16(a, b);
    float ha = __uint_as_float(hi << 16);
    float hb = __uint_as_float(hi & 0xffff0000u);
    lo = pk2_bf16(a - ha, b - hb);
}

struct RouterArgs {
    const float* cov;                      // [1024][512]
    const float* Wr1[3];                   // [512][256]
    const float* br1[3];                   // [256]
    const float* Wr2[3];                   // [256][7]
    const float* br2[3];                   // [7]
    const float* Wc[3];                    // [512][128]
    const float* bc[3];                    // [128]
    float* ws;
};

// grid (256, 3), block 384: each block = 4 consecutive b for one layer.
// (R2 version — measured best; the 192-thread variant regressed.)
__global__ __launch_bounds__(384) void router_kernel(RouterArgs a) {
    const int l   = blockIdx.y;
    const int b0  = blockIdx.x * 4;
    const int tid = threadIdx.x;

    __shared__ float4 covs[4][COV_ / 4];   // 8 KB
    __shared__ float  hr[4][256];          // 4 KB
    __shared__ float  susage[ES_];

    for (int f = tid; f < 512; f += 384) {
        const int bb = f >> 7, k4 = f & 127;
        covs[bb][k4] = ((const float4*)(a.cov + (size_t)(b0 + bb) * COV_))[k4];
    }
    if (tid < ES_) susage[tid] = 0.0f;
    __syncthreads();

    // Phase A: column-parallel GEMV, 4 b's per thread
    {
        const float* __restrict__ Wp;
        int stride; float bias;
        if (tid < 256) { Wp = a.Wr1[l] + tid;         stride = 256; bias = a.br1[l][tid]; }
        else           { Wp = a.Wc[l]  + (tid - 256); stride = 128; bias = a.bc[l][tid - 256]; }

        float acc[4] = {0.f, 0.f, 0.f, 0.f};
        #pragma unroll 4
        for (int k4 = 0; k4 < COV_ / 4; ++k4) {
            float w0 = Wp[(4 * k4 + 0) * stride];
            float w1 = Wp[(4 * k4 + 1) * stride];
            float w2 = Wp[(4 * k4 + 2) * stride];
            float w3 = Wp[(4 * k4 + 3) * stride];
            #pragma unroll
            for (int bb = 0; bb < 4; ++bb) {
                float4 c = covs[bb][k4];               // LDS broadcast
                acc[bb] = fmaf(c.x, w0, acc[bb]);
                acc[bb] = fmaf(c.y, w1, acc[bb]);
                acc[bb] = fmaf(c.z, w2, acc[bb]);
                acc[bb] = fmaf(c.w, w3, acc[bb]);
            }
        }
        if (tid < 256) {
            #pragma unroll
            for (int bb = 0; bb < 4; ++bb)
                hr[bb][tid] = fmaxf(acc[bb] + bias, 0.0f);
        } else {
            #pragma unroll
            for (int bb = 0; bb < 4; ++bb)
                a.ws[COVG_OFF + (size_t)(l * B_ + b0 + bb) * H_ + (tid - 256)] = acc[bb] + bias;
        }
    }
    __syncthreads();

    // Phase B: router logits + softmax, one wave per b (waves 0..3)
    {
        const int wave = tid >> 6;
        const int lane = tid & 63;
        if (wave < 4) {
            const int bb = wave;
            const int o = lane >> 3;      // 0..7 (7 invalid)
            const int g = lane & 7;
            float p = 0.0f;
            if (o < ES_) {
                #pragma unroll
                for (int m = 0; m < 32; ++m) {
                    const int k = g * 32 + m;
                    p = fmaf(hr[bb][k], a.Wr2[l][k * ES_ + o], p);
                }
            }
            p += __shfl_xor(p, 1);
            p += __shfl_xor(p, 2);
            p += __shfl_xor(p, 4);
            const float lg = p + ((o < ES_) ? a.br2[l][o] : 0.0f);
            float v[ES_];
            #pragma unroll
            for (int oo = 0; oo < ES_; ++oo) v[oo] = __shfl(lg, oo * 8, 64);
            if (lane == 0) {
                const int b = b0 + bb;
                float mx = v[0];
                #pragma unroll
                for (int oo = 1; oo < ES_; ++oo) mx = fmaxf(mx, v[oo]);
                float ex[ES_]; float s = 0.0f;
                #pragma unroll
                for (int oo = 0; oo < ES_; ++oo) { ex[oo] = __expf(v[oo] - mx); s += ex[oo]; }
                const float inv = 0.7f / s;            // (1-UW) * softmax
                float* wout = a.ws + W_WS_OFF + (size_t)(l * B_ + b) * 8;
                wout[0] = 0.3f;                        // UW/EU
                #pragma unroll
                for (int oo = 0; oo < ES_; ++oo) {
                    const float rwv = ex[oo] * inv;
                    wout[1 + oo] = rwv;
                    atomicAdd(&susage[oo], rwv);       // LDS pre-reduction
                }
            }
        }
    }
    __syncthreads();
    if (tid < ES_) atomicAdd(a.ws + USAGE_OFF + l * ES_ + tid, susage[tid]);
}

struct MainArgs {
    const float* y_t;        // [1024][256]
    const float* y0;         // [1024][256]
    const int*   t;          // [1024]
    const float* emb[3];     // [1001][128]
    const float* W1;         // [8][2][128]
    const float* W2;         // [8][128][128]
    const float* W3;         // [8][128][128]
    const float* b_[3];      // [8][128]
    const float* W4;         // [128]
    const float* b4;         // [1]
    float* ws;
    float* out;              // [1024*256] + [1] load
};

// grid 1024 (one b per block), 512 threads (8 waves), ~152 KB LDS -> 1 block/CU.
// bf16x3 emulated-fp32 GEMM on matrix cores; VALU around it minimized
// (fast softplus, v_cvt_pk_bf16_f32 pair splits).
__global__ __launch_bounds__(512, 2) void main_kernel(MainArgs a) {
    __shared__ unsigned short Ahi[256 * AT_STRIDE];   // 69632 B
    __shared__ unsigned short Alo[256 * AT_STRIDE];   // 69632 B
    __shared__ unsigned short WtBuf[2][128 * WT_STRIDE]; // 10240 B (hi, lo); aliased: L1 coeffs / pos
    __shared__ float GPs[2][128];    // gamma*(1+covg) for layers 2,3
    __shared__ float GPBs[2][128];   // GPs * bmix
    __shared__ float W4s[128];

    const int tid  = threadIdx.x;
    const int b    = blockIdx.x;
    const int lane = tid & 63;
    const int w    = tid >> 6;
    const int wm   = w >> 1;        // 0..3: token block (64)
    const int wn   = w & 1;         // 0..1: n block (64)
    const int nl   = lane & 15;
    const int quad = lane >> 4;
    const int tb   = a.t[b];

    float* L1f = (float*)WtBuf;     // [0:128)=A, [128:256)=B, [256:384)=C coeffs

    // ---- prologue: per-layer modulation vectors ----
    if (tid < 384) {
        const int l = tid >> 7, j = tid & 127;
        const float* wv = a.ws + W_WS_OFF + (size_t)(l * B_ + b) * 8;
        const float gamma = a.emb[l][tb * H_ + j];
        const float covg  = a.ws[COVG_OFF + (size_t)(l * B_ + b) * H_ + j];
        const float gp = gamma * (1.0f + covg);
        const float* bl = a.b_[l];
        float bm = 0.0f;
        #pragma unroll
        for (int e = 0; e < E_; ++e) bm = fmaf(wv[e], bl[e * H_ + j], bm);
        if (l == 0) {
            float s0 = 0.0f, s1 = 0.0f;
            #pragma unroll
            for (int e = 0; e < E_; ++e) {
                s0 = fmaf(wv[e], a.W1[e * 256 + j], s0);
                s1 = fmaf(wv[e], a.W1[e * 256 + 128 + j], s1);
            }
            L1f[j]       = gp * s0;
            L1f[128 + j] = gp * s1;
            L1f[256 + j] = gp * bm;
        } else {
            GPs[l - 1][j]  = gp;
            GPBs[l - 1][j] = gp * bm;
        }
    }
    if (tid < 128) W4s[tid] = a.W4[tid];
    __syncthreads();

    // ---- layer 1 (nin=2): 2 threads per token, write At hi/lo ----
    {
        const int tok = tid >> 1;
        const int jh  = (tid & 1) * 64;
        const float x0 = a.y_t[b * S_ + tok];
        const float x1 = a.y0[b * S_ + tok];
        #pragma unroll
        for (int g = 0; g < 8; ++g) {
            const int jb = jh + g * 8;
            unsigned hp[4], lp[4];
            #pragma unroll
            for (int p = 0; p < 4; ++p) {
                const int j0 = jb + 2 * p;
                float m0 = fmaf(x0, L1f[j0],     fmaf(x1, L1f[128 + j0],     L1f[256 + j0]));
                float m1 = fmaf(x0, L1f[j0 + 1], fmaf(x1, L1f[128 + j0 + 1], L1f[256 + j0 + 1]));
                split_pair(softplus_f(m0), softplus_f(m1), hp[p], lp[p]);
            }
            *(uint4*)&Ahi[tok * AT_STRIDE + jb] = make_uint4(hp[0], hp[1], hp[2], hp[3]);
            *(uint4*)&Alo[tok * AT_STRIDE + jb] = make_uint4(lp[0], lp[1], lp[2], lp[3]);
        }
    }
    // (first chunk barrier below synchronizes At)

    const int bj  = tid & 127;     // Weff-build: column j
    const int bkg = tid >> 7;      // Weff-build: k-group (8 k's)

    for (int L = 0; L < 2; ++L) {
        const float* __restrict__ Wg = L ? a.W3 : a.W2;
        const float* wv = a.ws + W_WS_OFF + (size_t)((L + 1) * B_ + b) * 8;
        float we[E_];
        #pragma unroll
        for (int e = 0; e < E_; ++e) we[e] = wv[e];

        f32x4 acc[4][4];
        #pragma unroll
        for (int mt = 0; mt < 4; ++mt)
            #pragma unroll
            for (int nt = 0; nt < 4; ++nt)
                acc[mt][nt] = (f32x4){0.f, 0.f, 0.f, 0.f};

        // Weff chunk builder: 8 k's x 1 column per thread -> packed hi/lo dwords
        unsigned bh[4], blo_[4];
        auto build = [&](int kc) {
            float bacc[8] = {0,0,0,0,0,0,0,0};
            const float* base = Wg + (size_t)(kc * 32 + bkg * 8) * H_ + bj;
            #pragma unroll
            for (int e = 0; e < E_; ++e) {
                const float* p = base + (size_t)e * (H_ * H_);
                const float wE = we[e];
                #pragma unroll
                for (int i = 0; i < 8; ++i)
                    bacc[i] = fmaf(wE, p[i * H_], bacc[i]);
            }
            #pragma unroll
            for (int i = 0; i < 4; ++i)
                split_pair(bacc[2 * i], bacc[2 * i + 1], bh[i], blo_[i]);
        };

        build(0);

        for (int kc = 0; kc < 4; ++kc) {
            __syncthreads();   // prev GEMM done reading Wt; At writes visible (kc==0)
            *(uint4*)&WtBuf[0][bj * WT_STRIDE + bkg * 8] = make_uint4(bh[0], bh[1], bh[2], bh[3]);
            *(uint4*)&WtBuf[1][bj * WT_STRIDE + bkg * 8] = make_uint4(blo_[0], blo_[1], blo_[2], blo_[3]);
            __syncthreads();

            // GEMM k-step (K=32)
            const int ka = kc * 32 + quad * 8;
            bf16x8 Af[4], Al[4], Bf[4], Bl[4];
            #pragma unroll
            for (int mt = 0; mt < 4; ++mt) {
                const int row = (wm * 64 + mt * 16 + nl) * AT_STRIDE + ka;
                Af[mt] = *(const bf16x8*)&Ahi[row];
                Al[mt] = *(const bf16x8*)&Alo[row];
            }
            #pragma unroll
            for (int nt = 0; nt < 4; ++nt) {
                const int row = (wn * 64 + nt * 16 + nl) * WT_STRIDE + quad * 8;
                Bf[nt] = *(const bf16x8*)&WtBuf[0][row];
                Bl[nt] = *(const bf16x8*)&WtBuf[1][row];
            }
            #pragma unroll
            for (int mt = 0; mt < 4; ++mt)
                #pragma unroll
                for (int nt = 0; nt < 4; ++nt) {
                    acc[mt][nt] = __builtin_amdgcn_mfma_f32_16x16x32_bf16(Af[mt], Bf[nt], acc[mt][nt], 0, 0, 0);
                    acc[mt][nt] = __builtin_amdgcn_mfma_f32_16x16x32_bf16(Af[mt], Bl[nt], acc[mt][nt], 0, 0, 0);
                    acc[mt][nt] = __builtin_amdgcn_mfma_f32_16x16x32_bf16(Al[mt], Bf[nt], acc[mt][nt], 0, 0, 0);
                }

            if (kc < 3) build(kc + 1);
        }
        __syncthreads();   // all GEMM reads of At / Wt done

        if (L == 0) {
            // epilogue layer2 -> At (hi/lo); C layout: n=nl(+16*nt), tok=quad*4+r(+16*mt)
            #pragma unroll
            for (int nt = 0; nt < 4; ++nt) {
                const int n = wn * 64 + nt * 16 + nl;
                const float gp = GPs[0][n], gpb = GPBs[0][n];
                #pragma unroll
                for (int mt = 0; mt < 4; ++mt) {
                    const int tok0 = wm * 64 + mt * 16 + quad * 4;
                    #pragma unroll
                    for (int rp = 0; rp < 2; ++rp) {
                        const float h0 = softplus_f(fmaf(gp, acc[mt][nt][2 * rp],     gpb));
                        const float h1 = softplus_f(fmaf(gp, acc[mt][nt][2 * rp + 1], gpb));
                        unsigned hh, ll;
                        split_pair(h0, h1, hh, ll);
                        const int t0 = tok0 + 2 * rp;
                        Ahi[t0 * AT_STRIDE + n]       = (unsigned short)hh;
                        Ahi[(t0 + 1) * AT_STRIDE + n] = (unsigned short)(hh >> 16);
                        Alo[t0 * AT_STRIDE + n]       = (unsigned short)ll;
                        Alo[(t0 + 1) * AT_STRIDE + n] = (unsigned short)(ll >> 16);
                    }
                }
            }
        } else {
            // epilogue layer3 fused with h3 @ W4
            float po[4][4];
            #pragma unroll
            for (int mt = 0; mt < 4; ++mt)
                #pragma unroll
                for (int r = 0; r < 4; ++r) po[mt][r] = 0.0f;
            #pragma unroll
            for (int nt = 0; nt < 4; ++nt) {
                const int n = wn * 64 + nt * 16 + nl;
                const float gp = GPs[1][n], gpb = GPBs[1][n], w4 = W4s[n];
                #pragma unroll
                for (int mt = 0; mt < 4; ++mt)
                    #pragma unroll
                    for (int r = 0; r < 4; ++r) {
                        const float h = softplus_f(fmaf(gp, acc[mt][nt][r], gpb));
                        po[mt][r] = fmaf(h, w4, po[mt][r]);
                    }
            }
            #pragma unroll
            for (int mt = 0; mt < 4; ++mt)
                #pragma unroll
                for (int r = 0; r < 4; ++r) {
                    po[mt][r] += __shfl_xor(po[mt][r], 1);
                    po[mt][r] += __shfl_xor(po[mt][r], 2);
                    po[mt][r] += __shfl_xor(po[mt][r], 4);
                    po[mt][r] += __shfl_xor(po[mt][r], 8);
                }
            float* pos = (float*)WtBuf;   // Wt free after post-loop barrier
            if (nl == 0) {
                #pragma unroll
                for (int mt = 0; mt < 4; ++mt)
                    #pragma unroll
                    for (int r = 0; r < 4; ++r)
                        pos[(wm * 64 + mt * 16 + quad * 4 + r) * 2 + wn] = po[mt][r];
            }
            __syncthreads();
            if (tid < 256)
                a.out[b * S_ + tid] = pos[2 * tid] + pos[2 * tid + 1] + a.b4[0];
        }
    }

    // load-balance scalar (router completed before this kernel)
    if (b == 0 && tid == 0) {
        float ld = 0.0f;
        for (int l = 0; l < 3; ++l)
            for (int o = 0; o < ES_; ++o) {
                float u = a.ws[USAGE_OFF + l * ES_ + o] * (1.0f / (float)B_);
                float d = u - (1.0f / (float)ES_);
                ld = fmaf(d, d, ld);
            }
        a.out[B_ * S_] = ld * (1.0f / (float)ES_);
    }
}

extern "C" void kernel_launch(void* const* d_in, const int* in_sizes, int n_in,
                              void* d_out, int out_size, void* d_ws, size_t ws_size,
                              hipStream_t stream) {
    (void)in_sizes; (void)n_in; (void)out_size; (void)ws_size;

    RouterArgs ra;
    ra.cov = (const float*)d_in[2];
    ra.ws  = (float*)d_ws;

    MainArgs ma;
    ma.y_t = (const float*)d_in[0];
    ma.y0  = (const float*)d_in[1];
    ma.t   = (const int*)d_in[3];
    for (int l = 0; l < 3; ++l) {
        const int base = 4 + l * 9;
        ma.emb[l] = (const float*)d_in[base + 0];
        ma.b_[l]  = (const float*)d_in[base + 2];
        ra.Wc[l]  = (const float*)d_in[base + 3];
        ra.bc[l]  = (const float*)d_in[base + 4];
        ra.Wr1[l] = (const float*)d_in[base + 5];
        ra.br1[l] = (const float*)d_in[base + 6];
        ra.Wr2[l] = (const float*)d_in[base + 7];
        ra.br2[l] = (const float*)d_in[base + 8];
    }
    ma.W1 = (const float*)d_in[4 + 0 * 9 + 1];
    ma.W2 = (const float*)d_in[4 + 1 * 9 + 1];
    ma.W3 = (const float*)d_in[4 + 2 * 9 + 1];
    ma.W4 = (const float*)d_in[31];
    ma.b4 = (const float*)d_in[32];
    ma.ws  = (float*)d_ws;
    ma.out = (float*)d_out;

    (void)hipMemsetAsync((char*)d_ws + USAGE_OFF * sizeof(float), 0, 24 * sizeof(float), stream);
    router_kernel<<<dim3(256, 3, 1), 384, 0, stream>>>(ra);
    main_kernel<<<dim3(1024, 1, 1), 512, 0, stream>>>(ma);
}

// Round 6
// 287.716 us; speedup vs baseline: 3.6060x; 1.1208x over previous
//
#include <hip/hip_runtime.h>
#include <hip/hip_bf16.h>
#include <math.h>

// Problem constants
#define B_    1024
#define S_    256
#define COV_  512
#define H_    128
#define E_    8
#define ES_   7

// ws layout (floats)
#define W_WS_OFF   0                       // [3][1024][8]
#define COVG_OFF   24576                   // [3][1024][128]
#define USAGE_OFF  417792                  // [3][7] padded

#define AT_STRIDE  136                     // 128 k + 8 pad (bf16), row = 272 B (16B aligned)
#define WT_STRIDE  40                      // 32 k + 8 pad (bf16), row = 80 B  (16B aligned)

typedef __attribute__((ext_vector_type(8))) short bf16x8;  // 8 bf16 = 4 VGPRs (MFMA A/B frag)
typedef __attribute__((ext_vector_type(4))) float f32x4;   // MFMA C/D frag

// Fast softplus: 2 HW transcendentals (v_exp_f32 / v_log_f32) + few VALU.
__device__ __forceinline__ float softplus_f(float x) {
    return fmaxf(x, 0.0f) + __logf(1.0f + __expf(-fabsf(x)));
}

// v_cvt_pk_bf16_f32: pack two fp32 -> two bf16 (RNE).
__device__ __forceinline__ unsigned pk2_bf16(float a, float b) {
    __hip_bfloat162 h = __float22bfloat162_rn(make_float2(a, b));
    return *reinterpret_cast<unsigned*>(&h);
}
__device__ __forceinline__ void split_pair(float a, float b, unsigned &hi, unsigned &lo) {
    hi = pk2_bf16(a, b);
    float ha = __uint_as_float(hi << 16);
    float hb = __uint_as_float(hi & 0xffff0000u);
    lo = pk2_bf16(a - ha, b - hb);
}

struct RouterArgs {
    const float* cov;                      // [1024][512]
    const float* Wr1[3];                   // [512][256]
    const float* br1[3];                   // [256]
    const float* Wr2[3];                   // [256][7]
    const float* br2[3];                   // [7]
    const float* Wc[3];                    // [512][128]
    const float* bc[3];                    // [128]
    float* ws;
};

// grid (256, 3), block 384: 4 b's per block, one column per thread.
// cov reads are WAVE-UNIFORM -> scalar loads (SGPR), zero LDS in the hot loop.
// (R2/R5 version staged cov in LDS: 512 ds_read_b128/wave made the router
//  LDS-pipe-bound at ~46+ us. This version's floor is L2 weight traffic.)
__global__ __launch_bounds__(384) void router_kernel(RouterArgs a) {
    const int l   = blockIdx.y;
    const int b0  = blockIdx.x * 4;
    const int tid = threadIdx.x;

    __shared__ float hr[4][256];
    __shared__ float susage[ES_];
    if (tid < ES_) susage[tid] = 0.0f;

    const float* __restrict__ c0 = a.cov + (size_t)(b0 + 0) * COV_;
    const float* __restrict__ c1 = a.cov + (size_t)(b0 + 1) * COV_;
    const float* __restrict__ c2 = a.cov + (size_t)(b0 + 2) * COV_;
    const float* __restrict__ c3 = a.cov + (size_t)(b0 + 3) * COV_;

    // Phase A: column-parallel GEMV; cols 0..255 = Wr1 (hr), 256..383 = Wc.
    {
        const float* __restrict__ Wp;
        int stride; float bias;
        if (tid < 256) { Wp = a.Wr1[l] + tid;         stride = 256; bias = a.br1[l][tid]; }
        else           { Wp = a.Wc[l]  + (tid - 256); stride = 128; bias = a.bc[l][tid - 256]; }

        float acc0 = 0.f, acc1 = 0.f, acc2 = 0.f, acc3 = 0.f;
        #pragma unroll 8
        for (int k = 0; k < COV_; ++k) {
            const float wv = Wp[(size_t)k * stride];   // coalesced across wave
            acc0 = fmaf(c0[k], wv, acc0);              // c*[k]: uniform -> s_load
            acc1 = fmaf(c1[k], wv, acc1);
            acc2 = fmaf(c2[k], wv, acc2);
            acc3 = fmaf(c3[k], wv, acc3);
        }
        if (tid < 256) {
            hr[0][tid] = fmaxf(acc0 + bias, 0.0f);
            hr[1][tid] = fmaxf(acc1 + bias, 0.0f);
            hr[2][tid] = fmaxf(acc2 + bias, 0.0f);
            hr[3][tid] = fmaxf(acc3 + bias, 0.0f);
        } else {
            const int j = tid - 256;
            a.ws[COVG_OFF + (size_t)(l * B_ + b0 + 0) * H_ + j] = acc0 + bias;
            a.ws[COVG_OFF + (size_t)(l * B_ + b0 + 1) * H_ + j] = acc1 + bias;
            a.ws[COVG_OFF + (size_t)(l * B_ + b0 + 2) * H_ + j] = acc2 + bias;
            a.ws[COVG_OFF + (size_t)(l * B_ + b0 + 3) * H_ + j] = acc3 + bias;
        }
    }
    __syncthreads();

    // Phase B: router logits + softmax, one wave per b (waves 0..3)
    {
        const int wave = tid >> 6;
        const int lane = tid & 63;
        if (wave < 4) {
            const int bb = wave;
            const int o = lane >> 3;      // 0..7 (7 invalid)
            const int g = lane & 7;
            float p = 0.0f;
            if (o < ES_) {
                #pragma unroll
                for (int m = 0; m < 32; ++m) {
                    const int k = g * 32 + m;
                    p = fmaf(hr[bb][k], a.Wr2[l][k * ES_ + o], p);
                }
            }
            p += __shfl_xor(p, 1);
            p += __shfl_xor(p, 2);
            p += __shfl_xor(p, 4);
            const float lg = p + ((o < ES_) ? a.br2[l][o] : 0.0f);
            float v[ES_];
            #pragma unroll
            for (int oo = 0; oo < ES_; ++oo) v[oo] = __shfl(lg, oo * 8, 64);
            if (lane == 0) {
                const int b = b0 + bb;
                float mx = v[0];
                #pragma unroll
                for (int oo = 1; oo < ES_; ++oo) mx = fmaxf(mx, v[oo]);
                float ex[ES_]; float s = 0.0f;
                #pragma unroll
                for (int oo = 0; oo < ES_; ++oo) { ex[oo] = __expf(v[oo] - mx); s += ex[oo]; }
                const float inv = 0.7f / s;            // (1-UW) * softmax
                float* wout = a.ws + W_WS_OFF + (size_t)(l * B_ + b) * 8;
                wout[0] = 0.3f;                        // UW/EU
                #pragma unroll
                for (int oo = 0; oo < ES_; ++oo) {
                    const float rwv = ex[oo] * inv;
                    wout[1 + oo] = rwv;
                    atomicAdd(&susage[oo], rwv);       // LDS pre-reduction
                }
            }
        }
    }
    __syncthreads();
    if (tid < ES_) atomicAdd(a.ws + USAGE_OFF + l * ES_ + tid, susage[tid]);
}

struct MainArgs {
    const float* y_t;        // [1024][256]
    const float* y0;         // [1024][256]
    const int*   t;          // [1024]
    const float* emb[3];     // [1001][128]
    const float* W1;         // [8][2][128]
    const float* W2;         // [8][128][128]
    const float* W3;         // [8][128][128]
    const float* b_[3];      // [8][128]
    const float* W4;         // [128]
    const float* b4;         // [1]
    float* ws;
    float* out;              // [1024*256] + [1] load
};

// grid 1024 (one b per block), 1024 threads (16 waves), ~158.5 KB LDS
// -> 1 block/CU but 4 waves/SIMD (vs 2 in R5): latency hiding for the
// fixed VALU work (softplus/splits/Weff-build). Wave tile 32 tok x 64 n.
__global__ __launch_bounds__(1024, 4) void main_kernel(MainArgs a) {
    __shared__ unsigned short Ahi[256 * AT_STRIDE];      // 69632 B
    __shared__ unsigned short Alo[256 * AT_STRIDE];      // 69632 B
    __shared__ unsigned short WtBuf[2][128 * WT_STRIDE]; // 20480 B; aliased: L1 coeffs / pos
    __shared__ float GPs[2][128];    // gamma*(1+covg) for layers 2,3
    __shared__ float GPBs[2][128];   // GPs * bmix
    __shared__ float W4s[128];

    const int tid  = threadIdx.x;
    const int b    = blockIdx.x;
    const int lane = tid & 63;
    const int w    = tid >> 6;      // 0..15
    const int wm   = w >> 1;        // 0..7: token block (32)
    const int wn   = w & 1;         // 0..1: n block (64)
    const int nl   = lane & 15;
    const int quad = lane >> 4;
    const int tb   = a.t[b];

    float* L1f = (float*)WtBuf;     // [0:128)=A, [128:256)=B, [256:384)=C coeffs

    // ---- prologue: per-layer modulation vectors ----
    if (tid < 384) {
        const int l = tid >> 7, j = tid & 127;
        const float* wv = a.ws + W_WS_OFF + (size_t)(l * B_ + b) * 8;
        const float gamma = a.emb[l][tb * H_ + j];
        const float covg  = a.ws[COVG_OFF + (size_t)(l * B_ + b) * H_ + j];
        const float gp = gamma * (1.0f + covg);
        const float* bl = a.b_[l];
        float bm = 0.0f;
        #pragma unroll
        for (int e = 0; e < E_; ++e) bm = fmaf(wv[e], bl[e * H_ + j], bm);
        if (l == 0) {
            float s0 = 0.0f, s1 = 0.0f;
            #pragma unroll
            for (int e = 0; e < E_; ++e) {
                s0 = fmaf(wv[e], a.W1[e * 256 + j], s0);
                s1 = fmaf(wv[e], a.W1[e * 256 + 128 + j], s1);
            }
            L1f[j]       = gp * s0;
            L1f[128 + j] = gp * s1;
            L1f[256 + j] = gp * bm;
        } else {
            GPs[l - 1][j]  = gp;
            GPBs[l - 1][j] = gp * bm;
        }
    }
    if (tid < 128) W4s[tid] = a.W4[tid];
    __syncthreads();

    // ---- layer 1 (nin=2): 4 threads per token, write At hi/lo ----
    {
        const int tok = tid >> 2;
        const int jh  = (tid & 3) * 32;
        const float x0 = a.y_t[b * S_ + tok];
        const float x1 = a.y0[b * S_ + tok];
        #pragma unroll
        for (int g = 0; g < 4; ++g) {
            const int jb = jh + g * 8;
            unsigned hp[4], lp[4];
            #pragma unroll
            for (int p = 0; p < 4; ++p) {
                const int j0 = jb + 2 * p;
                float m0 = fmaf(x0, L1f[j0],     fmaf(x1, L1f[128 + j0],     L1f[256 + j0]));
                float m1 = fmaf(x0, L1f[j0 + 1], fmaf(x1, L1f[128 + j0 + 1], L1f[256 + j0 + 1]));
                split_pair(softplus_f(m0), softplus_f(m1), hp[p], lp[p]);
            }
            *(uint4*)&Ahi[tok * AT_STRIDE + jb] = make_uint4(hp[0], hp[1], hp[2], hp[3]);
            *(uint4*)&Alo[tok * AT_STRIDE + jb] = make_uint4(lp[0], lp[1], lp[2], lp[3]);
        }
    }
    // (first chunk barrier below synchronizes At)

    const int bj  = tid & 127;     // Weff-build: column j
    const int bkg = tid >> 7;      // Weff-build: k-group (4 k's), 0..7

    for (int L = 0; L < 2; ++L) {
        const float* __restrict__ Wg = L ? a.W3 : a.W2;
        const float* wv = a.ws + W_WS_OFF + (size_t)((L + 1) * B_ + b) * 8;
        float we[E_];
        #pragma unroll
        for (int e = 0; e < E_; ++e) we[e] = wv[e];

        f32x4 acc[2][4];
        #pragma unroll
        for (int mt = 0; mt < 2; ++mt)
            #pragma unroll
            for (int nt = 0; nt < 4; ++nt)
                acc[mt][nt] = (f32x4){0.f, 0.f, 0.f, 0.f};

        // Weff chunk builder: 4 k's x 1 column per thread
        unsigned bh[2], blo_[2];
        auto build = [&](int kc) {
            float bacc[4] = {0.f, 0.f, 0.f, 0.f};
            const float* base = Wg + (size_t)(kc * 32 + bkg * 4) * H_ + bj;
            #pragma unroll
            for (int e = 0; e < E_; ++e) {
                const float* p = base + (size_t)e * (H_ * H_);
                const float wE = we[e];
                #pragma unroll
                for (int i = 0; i < 4; ++i)
                    bacc[i] = fmaf(wE, p[i * H_], bacc[i]);
            }
            split_pair(bacc[0], bacc[1], bh[0], blo_[0]);
            split_pair(bacc[2], bacc[3], bh[1], blo_[1]);
        };

        build(0);

        for (int kc = 0; kc < 4; ++kc) {
            __syncthreads();   // prev GEMM done reading Wt; At writes visible (kc==0)
            *(uint2*)&WtBuf[0][bj * WT_STRIDE + bkg * 4] = make_uint2(bh[0], bh[1]);
            *(uint2*)&WtBuf[1][bj * WT_STRIDE + bkg * 4] = make_uint2(blo_[0], blo_[1]);
            __syncthreads();

            // GEMM k-step (K=32)
            const int ka = kc * 32 + quad * 8;
            bf16x8 Af[2], Al[2], Bf[4], Bl[4];
            #pragma unroll
            for (int mt = 0; mt < 2; ++mt) {
                const int row = (wm * 32 + mt * 16 + nl) * AT_STRIDE + ka;
                Af[mt] = *(const bf16x8*)&Ahi[row];
                Al[mt] = *(const bf16x8*)&Alo[row];
            }
            #pragma unroll
            for (int nt = 0; nt < 4; ++nt) {
                const int row = (wn * 64 + nt * 16 + nl) * WT_STRIDE + quad * 8;
                Bf[nt] = *(const bf16x8*)&WtBuf[0][row];
                Bl[nt] = *(const bf16x8*)&WtBuf[1][row];
            }
            #pragma unroll
            for (int mt = 0; mt < 2; ++mt)
                #pragma unroll
                for (int nt = 0; nt < 4; ++nt) {
                    acc[mt][nt] = __builtin_amdgcn_mfma_f32_16x16x32_bf16(Af[mt], Bf[nt], acc[mt][nt], 0, 0, 0);
                    acc[mt][nt] = __builtin_amdgcn_mfma_f32_16x16x32_bf16(Af[mt], Bl[nt], acc[mt][nt], 0, 0, 0);
                    acc[mt][nt] = __builtin_amdgcn_mfma_f32_16x16x32_bf16(Al[mt], Bf[nt], acc[mt][nt], 0, 0, 0);
                }

            if (kc < 3) build(kc + 1);
        }
        __syncthreads();   // all GEMM reads of At / Wt done

        if (L == 0) {
            // epilogue layer2 -> At (hi/lo); C layout: n=nl(+16*nt), tok=quad*4+r(+16*mt)
            #pragma unroll
            for (int nt = 0; nt < 4; ++nt) {
                const int n = wn * 64 + nt * 16 + nl;
                const float gp = GPs[0][n], gpb = GPBs[0][n];
                #pragma unroll
                for (int mt = 0; mt < 2; ++mt) {
                    const int tok0 = wm * 32 + mt * 16 + quad * 4;
                    #pragma unroll
                    for (int rp = 0; rp < 2; ++rp) {
                        const float h0 = softplus_f(fmaf(gp, acc[mt][nt][2 * rp],     gpb));
                        const float h1 = softplus_f(fmaf(gp, acc[mt][nt][2 * rp + 1], gpb));
                        unsigned hh, ll;
                        split_pair(h0, h1, hh, ll);
                        const int t0 = tok0 + 2 * rp;
                        Ahi[t0 * AT_STRIDE + n]       = (unsigned short)hh;
                        Ahi[(t0 + 1) * AT_STRIDE + n] = (unsigned short)(hh >> 16);
                        Alo[t0 * AT_STRIDE + n]       = (unsigned short)ll;
                        Alo[(t0 + 1) * AT_STRIDE + n] = (unsigned short)(ll >> 16);
                    }
                }
            }
        } else {
            // epilogue layer3 fused with h3 @ W4
            float po[2][4];
            #pragma unroll
            for (int mt = 0; mt < 2; ++mt)
                #pragma unroll
                for (int r = 0; r < 4; ++r) po[mt][r] = 0.0f;
            #pragma unroll
            for (int nt = 0; nt < 4; ++nt) {
                const int n = wn * 64 + nt * 16 + nl;
                const float gp = GPs[1][n], gpb = GPBs[1][n], w4 = W4s[n];
                #pragma unroll
                for (int mt = 0; mt < 2; ++mt)
                    #pragma unroll
                    for (int r = 0; r < 4; ++r) {
                        const float h = softplus_f(fmaf(gp, acc[mt][nt][r], gpb));
                        po[mt][r] = fmaf(h, w4, po[mt][r]);
                    }
            }
            #pragma unroll
            for (int mt = 0; mt < 2; ++mt)
                #pragma unroll
                for (int r = 0; r < 4; ++r) {
                    po[mt][r] += __shfl_xor(po[mt][r], 1);
                    po[mt][r] += __shfl_xor(po[mt][r], 2);
                    po[mt][r] += __shfl_xor(po[mt][r], 4);
                    po[mt][r] += __shfl_xor(po[mt][r], 8);
                }
            float* pos = (float*)WtBuf;   // Wt free after post-loop barrier
            if (nl == 0) {
                #pragma unroll
                for (int mt = 0; mt < 2; ++mt)
                    #pragma unroll
                    for (int r = 0; r < 4; ++r)
                        pos[(wm * 32 + mt * 16 + quad * 4 + r) * 2 + wn] = po[mt][r];
            }
            __syncthreads();
            if (tid < 256)
                a.out[b * S_ + tid] = pos[2 * tid] + pos[2 * tid + 1] + a.b4[0];
        }
    }

    // load-balance scalar (router completed before this kernel)
    if (b == 0 && tid == 0) {
        float ld = 0.0f;
        for (int l = 0; l < 3; ++l)
            for (int o = 0; o < ES_; ++o) {
                float u = a.ws[USAGE_OFF + l * ES_ + o] * (1.0f / (float)B_);
                float d = u - (1.0f / (float)ES_);
                ld = fmaf(d, d, ld);
            }
        a.out[B_ * S_] = ld * (1.0f / (float)ES_);
    }
}

extern "C" void kernel_launch(void* const* d_in, const int* in_sizes, int n_in,
                              void* d_out, int out_size, void* d_ws, size_t ws_size,
                              hipStream_t stream) {
    (void)in_sizes; (void)n_in; (void)out_size; (void)ws_size;

    RouterArgs ra;
    ra.cov = (const float*)d_in[2];
    ra.ws  = (float*)d_ws;

    MainArgs ma;
    ma.y_t = (const float*)d_in[0];
    ma.y0  = (const float*)d_in[1];
    ma.t   = (const int*)d_in[3];
    for (int l = 0; l < 3; ++l) {
        const int base = 4 + l * 9;
        ma.emb[l] = (const float*)d_in[base + 0];
        ma.b_[l]  = (const float*)d_in[base + 2];
        ra.Wc[l]  = (const float*)d_in[base + 3];
        ra.bc[l]  = (const float*)d_in[base + 4];
        ra.Wr1[l] = (const float*)d_in[base + 5];
        ra.br1[l] = (const float*)d_in[base + 6];
        ra.Wr2[l] = (const float*)d_in[base + 7];
        ra.br2[l] = (const float*)d_in[base + 8];
    }
    ma.W1 = (const float*)d_in[4 + 0 * 9 + 1];
    ma.W2 = (const float*)d_in[4 + 1 * 9 + 1];
    ma.W3 = (const float*)d_in[4 + 2 * 9 + 1];
    ma.W4 = (const float*)d_in[31];
    ma.b4 = (const float*)d_in[32];
    ma.ws  = (float*)d_ws;
    ma.out = (float*)d_out;

    (void)hipMemsetAsync((char*)d_ws + USAGE_OFF * sizeof(float), 0, 24 * sizeof(float), stream);
    router_kernel<<<dim3(256, 3, 1), 384, 0, stream>>>(ra);
    main_kernel<<<dim3(1024, 1, 1), 1024, 0, stream>>>(ma);
}